// Round 2
// baseline (324.193 us; speedup 1.0000x reference)
//
#include <hip/hip_runtime.h>
#include <hip/hip_bf16.h>

#define NB 64
#define NT 512
#define NH 768
#define NL 25
#define EST 28  // emission row stride in floats (16B aligned); slot 25 = maskf

__device__ __forceinline__ float readlane_f(float v, int k) {
  return __int_as_float(__builtin_amdgcn_readlane(__float_as_int(v), k));
}

// Kernel 1: em[row][l] = X[row,:] . W[:,l] + b[l]; em[row][25] = maskf
// 512 blocks x 64 threads, one row per thread. W transposed into LDS in two
// half-H stages (38.4 KB each) so broadcast ds_read_b128 feeds the fmacs.
__global__ __launch_bounds__(64) void emis_kernel(
    const float* __restrict__ X, const int* __restrict__ mask,
    const float* __restrict__ W, const float* __restrict__ bias,
    float* __restrict__ em) {
  __shared__ float Wt[NL * 384];  // [l][h_rel], 38400 B
  const int tid = threadIdx.x;
  const int row = blockIdx.x * 64 + tid;

  float acc[NL];
#pragma unroll
  for (int l = 0; l < NL; ++l) acc[l] = bias[l];

  const float4* xr = (const float4*)(X + (size_t)row * NH);

  for (int ph = 0; ph < 2; ++ph) {
    __syncthreads();
    // stage: Wt[l][hr] = W[(ph*384+hr)*25 + l]; source index ph*9600+i is
    // consecutive across threads -> coalesced
    for (int i = tid; i < NL * 384; i += 64) {
      int hr = i / NL;
      int l = i - hr * NL;
      Wt[l * 384 + hr] = W[ph * (384 * NL) + i];
    }
    __syncthreads();
    for (int hc = 0; hc < 96; ++hc) {
      float4 xv = xr[ph * 96 + hc];
#pragma unroll
      for (int l = 0; l < NL; ++l) {
        const float4 wv = *(const float4*)&Wt[l * 384 + hc * 4];  // broadcast
        acc[l] = fmaf(xv.x, wv.x, acc[l]);
        acc[l] = fmaf(xv.y, wv.y, acc[l]);
        acc[l] = fmaf(xv.z, wv.z, acc[l]);
        acc[l] = fmaf(xv.w, wv.w, acc[l]);
      }
    }
  }

  float mf = (float)mask[row];
  float4* o4 = (float4*)(em + (size_t)row * EST);
#pragma unroll
  for (int q = 0; q < 6; ++q) {
    float4 v;
    v.x = acc[q * 4 + 0];
    v.y = acc[q * 4 + 1];
    v.z = acc[q * 4 + 2];
    v.w = acc[q * 4 + 3];
    o4[q] = v;
  }
  float4 vl;
  vl.x = acc[24]; vl.y = mf; vl.z = 0.f; vl.w = 0.f;
  o4[6] = vl;
}

// Kernel 2: per-batch CRF log-likelihood. One block (one wave) per batch.
// Forward recursion kept in scaled-exp domain: alpha = c + ln(A).
// lane l (l<25) owns next-label l; Ecol[k] = exp(trans[k][l]).
// A broadcast via v_readlane -> SGPR operands of the fmac dot.
__global__ __launch_bounds__(64) void crf_kernel(
    const float* __restrict__ em, const int* __restrict__ labels,
    const int* __restrict__ mask, const float* __restrict__ trans,
    const float* __restrict__ start_t, const float* __restrict__ end_t,
    float* __restrict__ out) {
  const int b = blockIdx.x;
  const int lane = threadIdx.x;
  const int l = lane < NL ? lane : NL - 1;
  const float* __restrict__ emb = em + (size_t)b * NT * EST;
  const int* __restrict__ lb = labels + b * NT;
  const int* __restrict__ mk = mask + b * NT;

  // ---- numerator (wave-parallel, 8 timesteps per lane) ----
  float np = 0.f;
  int ms = 0;
#pragma unroll
  for (int i = 0; i < 8; ++i) {
    int t = lane + i * 64;
    int tag = lb[t];
    int m = mk[t];
    float emt = emb[t * EST + tag];
    ms += m;
    if (t == 0) {
      np += start_t[tag] + emt;  // first token unmasked per reference
    } else {
      int tagp = lb[t - 1];
      np += (trans[tagp * NL + tag] + emt) * (float)m;
    }
  }
#pragma unroll
  for (int off = 32; off > 0; off >>= 1) {
    np += __shfl_down(np, off, 64);
    ms += __shfl_down(ms, off, 64);
  }
  float num = 0.f;
  if (lane == 0) num = np + end_t[lb[ms - 1]];

  // ---- denominator: scaled-exp forward pass ----
  float Ecol[NL];
#pragma unroll
  for (int k = 0; k < NL; ++k) Ecol[k] = __expf(trans[k * NL + l]);

  float A = __expf(start_t[l] + emb[l]);  // alpha0, c=0
  float c = 0.f, sc = 1.f, ei_ln2 = 0.f;
  const int j = lane < NL ? lane : NL;  // lanes>=25 fetch the mask slot

  float p1 = emb[1 * EST + j];
  float p2 = emb[2 * EST + j];
  float p3 = emb[3 * EST + j];
  float p4 = emb[4 * EST + j];

  for (int t = 1; t < NT; ++t) {
    float emv = p1;
    p1 = p2; p2 = p3; p3 = p4;
    int tp = t + 4; tp = tp < NT ? tp : NT - 1;
    p4 = emb[tp * EST + j];

    float e_em = __expf(emv);  // off critical path (prefetched input)

    float Pv0 = 0.f, Pv1 = 0.f, Pv2 = 0.f, Pv3 = 0.f;
#pragma unroll
    for (int k = 0; k < NL; k += 4) {
      Pv0 = fmaf(readlane_f(A, k), Ecol[k], Pv0);
      if (k + 1 < NL) Pv1 = fmaf(readlane_f(A, k + 1), Ecol[k + 1], Pv1);
      if (k + 2 < NL) Pv2 = fmaf(readlane_f(A, k + 2), Ecol[k + 2], Pv2);
      if (k + 3 < NL) Pv3 = fmaf(readlane_f(A, k + 3), Ecol[k + 3], Pv3);
    }
    float g = ((Pv0 + Pv1) + (Pv2 + Pv3)) * e_em;

    float mfv = readlane_f(emv, 25);  // lane 25 prefetched maskf[t]
    float An = (mfv > 0.f) ? g : A;   // masked step keeps old alpha
    A = An * sc;                       // apply pending rescale...
    c += ei_ln2;                       // ...and account it in c (same iter)

    // next rescale factor from lane0's exponent (1-step delayed, bounded)
    float a0 = readlane_f(A, 0);
    int eb = (__float_as_int(a0) >> 23) & 255;
    int ei = (eb == 0) ? 0 : (eb - 127);
    sc = __int_as_float((127 - ei) << 23);  // 2^{-ei}
    ei_ln2 = (float)ei * 0.6931471805599453f;
  }

  // denom = c + ln( sum_k A_k * exp(end_k) )
  float v = (lane < NL) ? A * __expf(end_t[l]) : 0.f;
#pragma unroll
  for (int off = 32; off > 0; off >>= 1) v += __shfl_down(v, off, 64);
  if (lane == 0) {
    float denom = c + __logf(v);
    atomicAdd(out, (denom - num) * (1.0f / (float)NB));  // -mean accumulate
  }
}

extern "C" void kernel_launch(void* const* d_in, const int* in_sizes, int n_in,
                              void* d_out, int out_size, void* d_ws, size_t ws_size,
                              hipStream_t stream) {
  const float* X       = (const float*)d_in[0];
  const int*   mask    = (const int*)d_in[1];
  const int*   labels  = (const int*)d_in[2];
  const float* W       = (const float*)d_in[3];
  const float* bias    = (const float*)d_in[4];
  const float* trans   = (const float*)d_in[5];
  const float* start_t = (const float*)d_in[6];
  const float* end_t   = (const float*)d_in[7];
  float* out = (float*)d_out;
  float* em  = (float*)d_ws;  // needs 32768*28*4 = 3.67 MB

  hipMemsetAsync(out, 0, sizeof(float), stream);
  emis_kernel<<<512, 64, 0, stream>>>(X, mask, W, bias, em);
  crf_kernel<<<NB, 64, 0, stream>>>(em, labels, mask, trans, start_t, end_t, out);
}

// Round 3
// 256.764 us; speedup vs baseline: 1.2626x; 1.2626x over previous
//
#include <hip/hip_runtime.h>
#include <hip/hip_bf16.h>

#define NB 64
#define NT 512
#define NH 768
#define NL 25
#define EST 28  // emission row stride in floats (16B aligned); slot 25 = maskf

typedef __attribute__((ext_vector_type(8))) short bf16x8;
typedef __attribute__((ext_vector_type(4))) float f32x4;

__device__ __forceinline__ float readlane_f(float v, int k) {
  return __int_as_float(__builtin_amdgcn_readlane(__float_as_int(v), k));
}

__device__ __forceinline__ short f2bf(float x) {  // fp32 -> bf16 bits, RNE
  uint32_t u = __float_as_uint(x);
  uint32_t r = (u + 0x7fffu + ((u >> 16) & 1u)) >> 16;
  return (short)r;
}

// Kernel 1 (MFMA): em[row][l] = X[row,:].W[:,l] + b[l]; em[row][25] = maskf.
// mfma_f32_16x16x32_bf16; A = X rows (fp32->bf16 in-register), B = W staged
// as pre-packed bf16 fragments in LDS (2 n-tiles x 24 k-steps x 64 lanes).
// A-frag: row=lane&15, k=8*(lane>>4)+i (contiguous k — m92/m97-validated).
// C/D: col=lane&15, row=(lane>>4)*4+reg (m89-verified).
__global__ __launch_bounds__(256) void emis_mfma_kernel(
    const float* __restrict__ X, const int* __restrict__ mask,
    const float* __restrict__ W, const float* __restrict__ bias,
    float* __restrict__ em) {
  __shared__ bf16x8 Bf[2][24][64];  // 48 KB
  const int tid = threadIdx.x;

  // ---- stage W fragments (once per block; W is L2-resident, 75 KB) ----
#pragma unroll
  for (int it = 0; it < 12; ++it) {
    int idx = tid + it * 256;          // 0..3071 = (nt, ks, slane)
    int nt = idx / (24 * 64);
    int rem = idx - nt * (24 * 64);
    int ks = rem >> 6;
    int sl = rem & 63;
    int col = (sl & 15) + nt * 16;
    int kb = ks * 32 + (sl >> 4) * 8;
    bf16x8 f;
#pragma unroll
    for (int j = 0; j < 8; ++j) {
      float v = (col < NL) ? W[(kb + j) * NL + col] : 0.f;
      f[j] = f2bf(v);
    }
    Bf[nt][ks][sl] = f;  // consecutive 16B per thread: conflict-free
  }
  __syncthreads();

  // ---- main: one 16-row tile per wave ----
  const int wave = tid >> 6;
  const int lane = tid & 63;
  const int rowTile = blockIdx.x * 64 + wave * 16;
  const int row = rowTile + (lane & 15);
  const int koff = (lane >> 4) * 8;
  const float4* __restrict__ xr = (const float4*)(X + (size_t)row * NH + koff);

  f32x4 acc0 = {0.f, 0.f, 0.f, 0.f};
  f32x4 acc1 = {0.f, 0.f, 0.f, 0.f};
#pragma unroll 4
  for (int ks = 0; ks < 24; ++ks) {
    float4 xa = xr[ks * 8];
    float4 xb = xr[ks * 8 + 1];
    bf16x8 a;
    a[0] = f2bf(xa.x); a[1] = f2bf(xa.y); a[2] = f2bf(xa.z); a[3] = f2bf(xa.w);
    a[4] = f2bf(xb.x); a[5] = f2bf(xb.y); a[6] = f2bf(xb.z); a[7] = f2bf(xb.w);
    bf16x8 b0 = Bf[0][ks][lane];
    bf16x8 b1 = Bf[1][ks][lane];
    acc0 = __builtin_amdgcn_mfma_f32_16x16x32_bf16(a, b0, acc0, 0, 0, 0);
    acc1 = __builtin_amdgcn_mfma_f32_16x16x32_bf16(a, b1, acc1, 0, 0, 0);
  }

  // ---- epilogue: bias + store (+ maskf in slot 25) ----
  const int cg = lane & 15;
  const int rbase = rowTile + (lane >> 4) * 4;
  float b0v = bias[cg];
  float b1v = (cg < 9) ? bias[16 + cg] : 0.f;
#pragma unroll
  for (int r = 0; r < 4; ++r) {
    int ro = rbase + r;
    float* er = em + (size_t)ro * EST;
    er[cg] = acc0[r] + b0v;
    if (cg < 9)       er[16 + cg] = acc1[r] + b1v;
    else if (cg == 9) er[25] = (float)mask[ro];
  }
}

// Kernel 2: per-batch CRF log-likelihood. One block (one wave) per batch.
// Forward recursion kept in scaled-exp domain: alpha = c + ln(A).
// lane l (l<25) owns next-label l; Ecol[k] = exp(trans[k][l]).
// A broadcast via v_readlane -> SGPR operands of the fmac dot.
__global__ __launch_bounds__(64) void crf_kernel(
    const float* __restrict__ em, const int* __restrict__ labels,
    const int* __restrict__ mask, const float* __restrict__ trans,
    const float* __restrict__ start_t, const float* __restrict__ end_t,
    float* __restrict__ out) {
  const int b = blockIdx.x;
  const int lane = threadIdx.x;
  const int l = lane < NL ? lane : NL - 1;
  const float* __restrict__ emb = em + (size_t)b * NT * EST;
  const int* __restrict__ lb = labels + b * NT;
  const int* __restrict__ mk = mask + b * NT;

  // ---- numerator (wave-parallel, 8 timesteps per lane) ----
  float np = 0.f;
  int ms = 0;
#pragma unroll
  for (int i = 0; i < 8; ++i) {
    int t = lane + i * 64;
    int tag = lb[t];
    int m = mk[t];
    float emt = emb[t * EST + tag];
    ms += m;
    if (t == 0) {
      np += start_t[tag] + emt;  // first token unmasked per reference
    } else {
      int tagp = lb[t - 1];
      np += (trans[tagp * NL + tag] + emt) * (float)m;
    }
  }
#pragma unroll
  for (int off = 32; off > 0; off >>= 1) {
    np += __shfl_down(np, off, 64);
    ms += __shfl_down(ms, off, 64);
  }
  float num = 0.f;
  if (lane == 0) num = np + end_t[lb[ms - 1]];

  // ---- denominator: scaled-exp forward pass ----
  float Ecol[NL];
#pragma unroll
  for (int k = 0; k < NL; ++k) Ecol[k] = __expf(trans[k * NL + l]);

  float A = __expf(start_t[l] + emb[l]);  // alpha0, c=0
  float c = 0.f, sc = 1.f, ei_ln2 = 0.f;
  const int j = lane < NL ? lane : NL;  // lanes>=25 fetch the mask slot

  float p1 = emb[1 * EST + j];
  float p2 = emb[2 * EST + j];
  float p3 = emb[3 * EST + j];
  float p4 = emb[4 * EST + j];

  for (int t = 1; t < NT; ++t) {
    float emv = p1;
    p1 = p2; p2 = p3; p3 = p4;
    int tp = t + 4; tp = tp < NT ? tp : NT - 1;
    p4 = emb[tp * EST + j];

    float e_em = __expf(emv);  // off critical path (prefetched input)

    float Pv0 = 0.f, Pv1 = 0.f, Pv2 = 0.f, Pv3 = 0.f;
#pragma unroll
    for (int k = 0; k < NL; k += 4) {
      Pv0 = fmaf(readlane_f(A, k), Ecol[k], Pv0);
      if (k + 1 < NL) Pv1 = fmaf(readlane_f(A, k + 1), Ecol[k + 1], Pv1);
      if (k + 2 < NL) Pv2 = fmaf(readlane_f(A, k + 2), Ecol[k + 2], Pv2);
      if (k + 3 < NL) Pv3 = fmaf(readlane_f(A, k + 3), Ecol[k + 3], Pv3);
    }
    float g = ((Pv0 + Pv1) + (Pv2 + Pv3)) * e_em;

    float mfv = readlane_f(emv, 25);  // lane 25 prefetched maskf[t]
    float An = (mfv > 0.f) ? g : A;   // masked step keeps old alpha
    A = An * sc;                       // apply pending rescale...
    c += ei_ln2;                       // ...and account it in c (same iter)

    // next rescale factor from lane0's exponent (1-step delayed, bounded)
    float a0 = readlane_f(A, 0);
    int eb = (__float_as_int(a0) >> 23) & 255;
    int ei = (eb == 0) ? 0 : (eb - 127);
    sc = __int_as_float((127 - ei) << 23);  // 2^{-ei}
    ei_ln2 = (float)ei * 0.6931471805599453f;
  }

  // denom = c + ln( sum_k A_k * exp(end_k) )
  float v = (lane < NL) ? A * __expf(end_t[l]) : 0.f;
#pragma unroll
  for (int off = 32; off > 0; off >>= 1) v += __shfl_down(v, off, 64);
  if (lane == 0) {
    float denom = c + __logf(v);
    atomicAdd(out, (denom - num) * (1.0f / (float)NB));  // -mean accumulate
  }
}

extern "C" void kernel_launch(void* const* d_in, const int* in_sizes, int n_in,
                              void* d_out, int out_size, void* d_ws, size_t ws_size,
                              hipStream_t stream) {
  const float* X       = (const float*)d_in[0];
  const int*   mask    = (const int*)d_in[1];
  const int*   labels  = (const int*)d_in[2];
  const float* W       = (const float*)d_in[3];
  const float* bias    = (const float*)d_in[4];
  const float* trans   = (const float*)d_in[5];
  const float* start_t = (const float*)d_in[6];
  const float* end_t   = (const float*)d_in[7];
  float* out = (float*)d_out;
  float* em  = (float*)d_ws;  // needs 32768*28*4 = 3.67 MB

  hipMemsetAsync(out, 0, sizeof(float), stream);
  emis_mfma_kernel<<<512, 256, 0, stream>>>(X, mask, W, bias, em);
  crf_kernel<<<NB, 64, 0, stream>>>(em, labels, mask, trans, start_t, end_t, out);
}

// Round 4
// 202.871 us; speedup vs baseline: 1.5980x; 1.2657x over previous
//
#include <hip/hip_runtime.h>
#include <hip/hip_bf16.h>

#define NB 64
#define NT 512
#define NH 768
#define NL 25
#define EST 28  // emission row stride in floats (16B aligned); slot 25 = maskf
#define SEGS 8
#define SEGLEN 64

typedef __attribute__((ext_vector_type(8))) short bf16x8;
typedef __attribute__((ext_vector_type(4))) float f32x4;
typedef __attribute__((ext_vector_type(16))) float f32x16;

__device__ __forceinline__ float readlane_f(float v, int k) {
  return __int_as_float(__builtin_amdgcn_readlane(__float_as_int(v), k));
}

__device__ __forceinline__ short f2bf(float x) {  // fp32 -> bf16 bits, RNE
  uint32_t u = __float_as_uint(x);
  uint32_t r = (u + 0x7fffu + ((u >> 16) & 1u)) >> 16;
  return (short)r;
}

__device__ __forceinline__ int cvt_pk_bf16(float lo, float hi) {
  int r;
  asm("v_cvt_pk_bf16_f32 %0, %1, %2" : "=v"(r) : "v"(lo), "v"(hi));
  return r;
}

// Kernel 1 (MFMA): em[row][l] = X[row,:].W[:,l] + b[l]; em[row][25] = maskf.
__global__ __launch_bounds__(256) void emis_mfma_kernel(
    const float* __restrict__ X, const int* __restrict__ mask,
    const float* __restrict__ W, const float* __restrict__ bias,
    float* __restrict__ em) {
  __shared__ bf16x8 Bf[2][24][64];  // 48 KB
  const int tid = threadIdx.x;

#pragma unroll
  for (int it = 0; it < 12; ++it) {
    int idx = tid + it * 256;
    int nt = idx / (24 * 64);
    int rem = idx - nt * (24 * 64);
    int ks = rem >> 6;
    int sl = rem & 63;
    int col = (sl & 15) + nt * 16;
    int kb = ks * 32 + (sl >> 4) * 8;
    bf16x8 f;
#pragma unroll
    for (int j = 0; j < 8; ++j) {
      float v = (col < NL) ? W[(kb + j) * NL + col] : 0.f;
      f[j] = f2bf(v);
    }
    Bf[nt][ks][sl] = f;
  }
  __syncthreads();

  const int wave = tid >> 6;
  const int lane = tid & 63;
  const int rowTile = blockIdx.x * 64 + wave * 16;
  const int row = rowTile + (lane & 15);
  const int koff = (lane >> 4) * 8;
  const float4* __restrict__ xr = (const float4*)(X + (size_t)row * NH + koff);

  f32x4 acc0 = {0.f, 0.f, 0.f, 0.f};
  f32x4 acc1 = {0.f, 0.f, 0.f, 0.f};
#pragma unroll 4
  for (int ks = 0; ks < 24; ++ks) {
    float4 xa = xr[ks * 8];
    float4 xb = xr[ks * 8 + 1];
    bf16x8 a;
    a[0] = f2bf(xa.x); a[1] = f2bf(xa.y); a[2] = f2bf(xa.z); a[3] = f2bf(xa.w);
    a[4] = f2bf(xb.x); a[5] = f2bf(xb.y); a[6] = f2bf(xb.z); a[7] = f2bf(xb.w);
    bf16x8 b0 = Bf[0][ks][lane];
    bf16x8 b1 = Bf[1][ks][lane];
    acc0 = __builtin_amdgcn_mfma_f32_16x16x32_bf16(a, b0, acc0, 0, 0, 0);
    acc1 = __builtin_amdgcn_mfma_f32_16x16x32_bf16(a, b1, acc1, 0, 0, 0);
  }

  const int cg = lane & 15;
  const int rbase = rowTile + (lane >> 4) * 4;
  float b0v = bias[cg];
  float b1v = (cg < 9) ? bias[16 + cg] : 0.f;
#pragma unroll
  for (int r = 0; r < 4; ++r) {
    int ro = rbase + r;
    float* er = em + (size_t)ro * EST;
    er[cg] = acc0[r] + b0v;
    if (cg < 9)       er[16 + cg] = acc1[r] + b1v;
    else if (cg == 9) er[25] = (float)mask[ro];
  }
}

// Kernel 2a: segment composition. Block = (chain b, segment s), 1 wave.
// D (32x32, rows=dest label l, cols=source label i) evolves as D <- E_t^T x D
// in scaled-exp domain via 2x mfma_f32_32x32x16_bf16 (K split 0..15 / 16..31).
// A-frag row l = lane&31 scaled exp(trans^T) * e^{em}*sc; B-frag rebuilt from
// the f32 C-layout output with cvt_pk + v_permlane32_swap_b32 each step.
// Any common k-permutation of the A/B frag layout cancels in the product, so
// only the verified C/D layout (col=lane&31, row=(reg&3)+8*(reg>>2)+4*(lane>>5))
// is load-bearing.
__global__ __launch_bounds__(64) void crf_seg_kernel(
    const float* __restrict__ em, const float* __restrict__ trans,
    float* __restrict__ Dg, float* __restrict__ Dc) {
  const int b = blockIdx.x >> 3;
  const int s = blockIdx.x & 7;
  const int lane = threadIdx.x;
  const int l = lane & 31;
  const int half = lane >> 5;
  const float* __restrict__ emb = em + (size_t)b * NT * EST;

  // Etf[l][k] = exp(trans[k][l]); k in [8h,8h+8) and [16+8h,16+8h+8)
  float Et0[8], Et1[8];
#pragma unroll
  for (int j = 0; j < 8; ++j) {
    int k0 = 8 * half + j;
    int k1 = 16 + 8 * half + j;
    Et0[j] = (l < NL) ? __expf(trans[k0 * NL + l]) : 0.f;
    Et1[j] = (l < NL && k1 < NL) ? __expf(trans[k1 * NL + l]) : 0.f;
  }

  // acc = identity in C-layout (fallback if every step masked)
  f32x16 acc;
#pragma unroll
  for (int r = 0; r < 16; ++r) {
    int row = (r & 3) + 8 * (r >> 2) + 4 * half;
    acc[r] = (row == l && l < NL) ? 1.f : 0.f;
  }

  // initial B frags = identity, built through cvt_pk so packing convention
  // matches the steady-state path.
  union Frag { int i[4]; bf16x8 v; };
  Frag B0, B1;
#pragma unroll
  for (int m = 0; m < 4; ++m) {
    int ka = 8 * half + 2 * m, kb = ka + 1;
    B0.i[m] = cvt_pk_bf16((ka == l && l < NL) ? 1.f : 0.f,
                          (kb == l && l < NL) ? 1.f : 0.f);
    int kc = 16 + 8 * half + 2 * m, kd = kc + 1;
    B1.i[m] = cvt_pk_bf16((kc == l && l < NL) ? 1.f : 0.f,
                          (kd == l && l < NL) ? 1.f : 0.f);
  }

  const int ts = 1 + s * SEGLEN;
  const int te = (ts + SEGLEN < NT) ? ts + SEGLEN : NT;
  const int c2 = (l < NL) ? l : NL;  // lanes l>=25 fetch the mask slot

  float c = 0.f, sc = 1.f, ei_ln2 = 0.f;

  float p0 = emb[ts * EST + c2];
  int i1 = ts + 1 < te ? ts + 1 : te - 1;
  int i2 = ts + 2 < te ? ts + 2 : te - 1;
  int i3 = ts + 3 < te ? ts + 3 : te - 1;
  float p1 = emb[i1 * EST + c2];
  float p2 = emb[i2 * EST + c2];
  float p3 = emb[i3 * EST + c2];

  for (int t = ts; t < te; ++t) {
    float emv = p0; p0 = p1; p1 = p2; p2 = p3;
    int tp = t + 4 < te ? t + 4 : te - 1;
    p3 = emb[tp * EST + c2];

    float mv = readlane_f(emv, 25);  // maskf[t]
    if (mv > 0.f) {
      float g = __expf(emv) * sc;  // pending rescale folded into A row scale
      c += ei_ln2;
      sc = 1.f; ei_ln2 = 0.f;

      Frag A0, A1;
#pragma unroll
      for (int m = 0; m < 4; ++m) {
        A0.i[m] = cvt_pk_bf16(Et0[2 * m] * g, Et0[2 * m + 1] * g);
        A1.i[m] = cvt_pk_bf16(Et1[2 * m] * g, Et1[2 * m + 1] * g);
      }
      f32x16 z;
#pragma unroll
      for (int r = 0; r < 16; ++r) z[r] = 0.f;
      z = __builtin_amdgcn_mfma_f32_32x32x16_bf16(A0.v, B0.v, z, 0, 0, 0);
      acc = __builtin_amdgcn_mfma_f32_32x32x16_bf16(A1.v, B1.v, z, 0, 0, 0);

      if ((t & 7) == 7) {  // resample rescale every 8 steps (delayed apply)
        float a0s = readlane_f(acc[0], 0);
        int eb = (__float_as_int(a0s) >> 23) & 255;
        int ei = (eb == 0) ? 0 : eb - 127;
        sc = __int_as_float((127 - ei) << 23);
        ei_ln2 = (float)ei * 0.6931471805599453f;
      }

      // acc (f32 C-layout) -> next-step B frags (bf16)
      int u0 = cvt_pk_bf16(acc[0], acc[1]);
      int u1 = cvt_pk_bf16(acc[2], acc[3]);
      int w0 = cvt_pk_bf16(acc[4], acc[5]);
      int w1 = cvt_pk_bf16(acc[6], acc[7]);
      asm volatile("v_permlane32_swap_b32 %0, %1" : "+v"(u0), "+v"(w0));
      asm volatile("v_permlane32_swap_b32 %0, %1" : "+v"(u1), "+v"(w1));
      B0.i[0] = u0; B0.i[1] = u1; B0.i[2] = w0; B0.i[3] = w1;
      int v0 = cvt_pk_bf16(acc[8], acc[9]);
      int v1 = cvt_pk_bf16(acc[10], acc[11]);
      int x0 = cvt_pk_bf16(acc[12], acc[13]);
      int x1 = cvt_pk_bf16(acc[14], acc[15]);
      asm volatile("v_permlane32_swap_b32 %0, %1" : "+v"(v0), "+v"(x0));
      asm volatile("v_permlane32_swap_b32 %0, %1" : "+v"(v1), "+v"(x1));
      B1.i[0] = v0; B1.i[1] = v1; B1.i[2] = x0; B1.i[3] = x1;
    }
  }

  float* dst = Dg + (size_t)(b * SEGS + s) * 32 * 32;
#pragma unroll
  for (int r = 0; r < 16; ++r) {
    int row = (r & 3) + 8 * (r >> 2) + 4 * half;
    dst[row * 32 + l] = acc[r];
  }
  if (lane == 0) Dc[b * SEGS + s] = c;
}

// Kernel 2b: merge. One wave per chain: numerator + alpha0 x (8 segment mats).
__global__ __launch_bounds__(64) void crf_merge_kernel(
    const float* __restrict__ em, const int* __restrict__ labels,
    const int* __restrict__ mask, const float* __restrict__ trans,
    const float* __restrict__ start_t, const float* __restrict__ end_t,
    const float* __restrict__ Dg, const float* __restrict__ Dc,
    float* __restrict__ out) {
  const int b = blockIdx.x;
  const int lane = threadIdx.x;
  const float* __restrict__ emb = em + (size_t)b * NT * EST;
  const int* __restrict__ lb = labels + b * NT;
  const int* __restrict__ mk = mask + b * NT;

  // ---- numerator ----
  float np = 0.f;
  int ms = 0;
#pragma unroll
  for (int i = 0; i < 8; ++i) {
    int t = lane + i * 64;
    int tag = lb[t];
    int m = mk[t];
    float emt = emb[t * EST + tag];
    ms += m;
    if (t == 0) {
      np += start_t[tag] + emt;
    } else {
      int tagp = lb[t - 1];
      np += (trans[tagp * NL + tag] + emt) * (float)m;
    }
  }
#pragma unroll
  for (int off = 32; off > 0; off >>= 1) {
    np += __shfl_down(np, off, 64);
    ms += __shfl_down(ms, off, 64);
  }
  float num = 0.f;
  if (lane == 0) num = np + end_t[lb[ms - 1]];

  // ---- alpha through 8 composed segment matrices ----
  const int l = lane & 31;
  float a = (lane < NL) ? __expf(start_t[lane] + emb[lane]) : 0.f;
  float c = 0.f;
  for (int s = 0; s < SEGS; ++s) {
    const float* Drow = Dg + ((size_t)(b * SEGS + s) * 32 + l) * 32;
    float a0 = 0.f, a1 = 0.f, a2 = 0.f, a3 = 0.f;
#pragma unroll
    for (int i = 0; i < NL; i += 4) {
      a0 = fmaf(Drow[i], readlane_f(a, i), a0);
      if (i + 1 < NL) a1 = fmaf(Drow[i + 1], readlane_f(a, i + 1), a1);
      if (i + 2 < NL) a2 = fmaf(Drow[i + 2], readlane_f(a, i + 2), a2);
      if (i + 3 < NL) a3 = fmaf(Drow[i + 3], readlane_f(a, i + 3), a3);
    }
    float an = (a0 + a1) + (a2 + a3);
    c += Dc[b * SEGS + s];
    float s0 = readlane_f(an, 0);
    int eb = (__float_as_int(s0) >> 23) & 255;
    int ei = (eb == 0) ? 0 : eb - 127;
    a = an * __int_as_float((127 - ei) << 23);
    c += (float)ei * 0.6931471805599453f;
  }

  float v = (lane < NL) ? a * __expf(end_t[lane]) : 0.f;
#pragma unroll
  for (int off = 32; off > 0; off >>= 1) v += __shfl_down(v, off, 64);
  if (lane == 0) {
    float denom = c + __logf(v);
    atomicAdd(out, (denom - num) * (1.0f / (float)NB));
  }
}

// Fallback serial CRF (proven exact) — used only if ws_size is too small.
__global__ __launch_bounds__(64) void crf_kernel(
    const float* __restrict__ em, const int* __restrict__ labels,
    const int* __restrict__ mask, const float* __restrict__ trans,
    const float* __restrict__ start_t, const float* __restrict__ end_t,
    float* __restrict__ out) {
  const int b = blockIdx.x;
  const int lane = threadIdx.x;
  const int l = lane < NL ? lane : NL - 1;
  const float* __restrict__ emb = em + (size_t)b * NT * EST;
  const int* __restrict__ lb = labels + b * NT;
  const int* __restrict__ mk = mask + b * NT;

  float np = 0.f;
  int ms = 0;
#pragma unroll
  for (int i = 0; i < 8; ++i) {
    int t = lane + i * 64;
    int tag = lb[t];
    int m = mk[t];
    float emt = emb[t * EST + tag];
    ms += m;
    if (t == 0) np += start_t[tag] + emt;
    else {
      int tagp = lb[t - 1];
      np += (trans[tagp * NL + tag] + emt) * (float)m;
    }
  }
#pragma unroll
  for (int off = 32; off > 0; off >>= 1) {
    np += __shfl_down(np, off, 64);
    ms += __shfl_down(ms, off, 64);
  }
  float num = 0.f;
  if (lane == 0) num = np + end_t[lb[ms - 1]];

  float Ecol[NL];
#pragma unroll
  for (int k = 0; k < NL; ++k) Ecol[k] = __expf(trans[k * NL + l]);

  float A = __expf(start_t[l] + emb[l]);
  float c = 0.f, sc = 1.f, ei_ln2 = 0.f;
  const int j = lane < NL ? lane : NL;

  float p1 = emb[1 * EST + j];
  float p2 = emb[2 * EST + j];
  float p3 = emb[3 * EST + j];
  float p4 = emb[4 * EST + j];

  for (int t = 1; t < NT; ++t) {
    float emv = p1;
    p1 = p2; p2 = p3; p3 = p4;
    int tp = t + 4; tp = tp < NT ? tp : NT - 1;
    p4 = emb[tp * EST + j];
    float e_em = __expf(emv);
    float Pv0 = 0.f, Pv1 = 0.f, Pv2 = 0.f, Pv3 = 0.f;
#pragma unroll
    for (int k = 0; k < NL; k += 4) {
      Pv0 = fmaf(readlane_f(A, k), Ecol[k], Pv0);
      if (k + 1 < NL) Pv1 = fmaf(readlane_f(A, k + 1), Ecol[k + 1], Pv1);
      if (k + 2 < NL) Pv2 = fmaf(readlane_f(A, k + 2), Ecol[k + 2], Pv2);
      if (k + 3 < NL) Pv3 = fmaf(readlane_f(A, k + 3), Ecol[k + 3], Pv3);
    }
    float g = ((Pv0 + Pv1) + (Pv2 + Pv3)) * e_em;
    float mfv = readlane_f(emv, 25);
    float An = (mfv > 0.f) ? g : A;
    A = An * sc;
    c += ei_ln2;
    float a0 = readlane_f(A, 0);
    int eb = (__float_as_int(a0) >> 23) & 255;
    int ei = (eb == 0) ? 0 : (eb - 127);
    sc = __int_as_float((127 - ei) << 23);
    ei_ln2 = (float)ei * 0.6931471805599453f;
  }

  float v = (lane < NL) ? A * __expf(end_t[l]) : 0.f;
#pragma unroll
  for (int off = 32; off > 0; off >>= 1) v += __shfl_down(v, off, 64);
  if (lane == 0) {
    float denom = c + __logf(v);
    atomicAdd(out, (denom - num) * (1.0f / (float)NB));
  }
}

extern "C" void kernel_launch(void* const* d_in, const int* in_sizes, int n_in,
                              void* d_out, int out_size, void* d_ws, size_t ws_size,
                              hipStream_t stream) {
  const float* X       = (const float*)d_in[0];
  const int*   mask    = (const int*)d_in[1];
  const int*   labels  = (const int*)d_in[2];
  const float* W       = (const float*)d_in[3];
  const float* bias    = (const float*)d_in[4];
  const float* trans   = (const float*)d_in[5];
  const float* start_t = (const float*)d_in[6];
  const float* end_t   = (const float*)d_in[7];
  float* out = (float*)d_out;

  float* em = (float*)d_ws;                                 // 3.67 MB
  float* Dg = (float*)((char*)d_ws + (4u << 20));           // 2.00 MB
  float* Dc = (float*)((char*)d_ws + (4u << 20) + (2u << 20));  // 2 KB

  hipMemsetAsync(out, 0, sizeof(float), stream);
  emis_mfma_kernel<<<512, 256, 0, stream>>>(X, mask, W, bias, em);
  if (ws_size >= (7u << 20)) {
    crf_seg_kernel<<<NB * SEGS, 64, 0, stream>>>(em, trans, Dg, Dc);
    crf_merge_kernel<<<NB, 64, 0, stream>>>(em, labels, mask, trans, start_t,
                                            end_t, Dg, Dc, out);
  } else {
    crf_kernel<<<NB, 64, 0, stream>>>(em, labels, mask, trans, start_t, end_t, out);
  }
}

// Round 5
// 198.673 us; speedup vs baseline: 1.6318x; 1.0211x over previous
//
#include <hip/hip_runtime.h>
#include <hip/hip_bf16.h>

#define NB 64
#define NT 512
#define NH 768
#define NL 25
#define EST 28  // emission row stride in floats (16B aligned); slot 25 = maskf
#define SEGS 32
#define SEGLEN 16

typedef __attribute__((ext_vector_type(8))) short bf16x8;
typedef __attribute__((ext_vector_type(4))) float f32x4;
typedef __attribute__((ext_vector_type(16))) float f32x16;

__device__ __forceinline__ float readlane_f(float v, int k) {
  return __int_as_float(__builtin_amdgcn_readlane(__float_as_int(v), k));
}

__device__ __forceinline__ short f2bf(float x) {  // fp32 -> bf16 bits, RNE
  uint32_t u = __float_as_uint(x);
  uint32_t r = (u + 0x7fffu + ((u >> 16) & 1u)) >> 16;
  return (short)r;
}

__device__ __forceinline__ int cvt_pk_bf16(float lo, float hi) {
  int r;
  asm("v_cvt_pk_bf16_f32 %0, %1, %2" : "=v"(r) : "v"(lo), "v"(hi));
  return r;
}

// Kernel 1 (MFMA): em[row][l] = X[row,:].W[:,l] + b[l]; em[row][25] = maskf.
__global__ __launch_bounds__(256) void emis_mfma_kernel(
    const float* __restrict__ X, const int* __restrict__ mask,
    const float* __restrict__ W, const float* __restrict__ bias,
    float* __restrict__ em) {
  __shared__ bf16x8 Bf[2][24][64];  // 48 KB
  const int tid = threadIdx.x;

#pragma unroll
  for (int it = 0; it < 12; ++it) {
    int idx = tid + it * 256;
    int nt = idx / (24 * 64);
    int rem = idx - nt * (24 * 64);
    int ks = rem >> 6;
    int sl = rem & 63;
    int col = (sl & 15) + nt * 16;
    int kb = ks * 32 + (sl >> 4) * 8;
    bf16x8 f;
#pragma unroll
    for (int j = 0; j < 8; ++j) {
      float v = (col < NL) ? W[(kb + j) * NL + col] : 0.f;
      f[j] = f2bf(v);
    }
    Bf[nt][ks][sl] = f;
  }
  __syncthreads();

  const int wave = tid >> 6;
  const int lane = tid & 63;
  const int rowTile = blockIdx.x * 64 + wave * 16;
  const int row = rowTile + (lane & 15);
  const int koff = (lane >> 4) * 8;
  const float4* __restrict__ xr = (const float4*)(X + (size_t)row * NH + koff);

  f32x4 acc0 = {0.f, 0.f, 0.f, 0.f};
  f32x4 acc1 = {0.f, 0.f, 0.f, 0.f};
#pragma unroll 4
  for (int ks = 0; ks < 24; ++ks) {
    float4 xa = xr[ks * 8];
    float4 xb = xr[ks * 8 + 1];
    bf16x8 a;
    a[0] = f2bf(xa.x); a[1] = f2bf(xa.y); a[2] = f2bf(xa.z); a[3] = f2bf(xa.w);
    a[4] = f2bf(xb.x); a[5] = f2bf(xb.y); a[6] = f2bf(xb.z); a[7] = f2bf(xb.w);
    bf16x8 b0 = Bf[0][ks][lane];
    bf16x8 b1 = Bf[1][ks][lane];
    acc0 = __builtin_amdgcn_mfma_f32_16x16x32_bf16(a, b0, acc0, 0, 0, 0);
    acc1 = __builtin_amdgcn_mfma_f32_16x16x32_bf16(a, b1, acc1, 0, 0, 0);
  }

  const int cg = lane & 15;
  const int rbase = rowTile + (lane >> 4) * 4;
  float b0v = bias[cg];
  float b1v = (cg < 9) ? bias[16 + cg] : 0.f;
#pragma unroll
  for (int r = 0; r < 4; ++r) {
    int ro = rbase + r;
    float* er = em + (size_t)ro * EST;
    er[cg] = acc0[r] + b0v;
    if (cg < 9)       er[16 + cg] = acc1[r] + b1v;
    else if (cg == 9) er[25] = (float)mask[ro];
  }
}

// Kernel 2a: segment composition. Block = (chain b, segment s), 1 wave.
// D (32x32, rows=dest label l, cols=source label i) evolves as D <- E_t^T x D
// in scaled-exp domain via 2x mfma_f32_32x32x16_bf16 (K split 0..15 / 16..31).
// SEGLEN=16 keeps the serial per-block chain short; composition is pushed to
// the parallel-loadable merge.
__global__ __launch_bounds__(64) void crf_seg_kernel(
    const float* __restrict__ em, const float* __restrict__ trans,
    float* __restrict__ Dg, float* __restrict__ Dc) {
  const int b = blockIdx.x / SEGS;
  const int s = blockIdx.x % SEGS;
  const int lane = threadIdx.x;
  const int l = lane & 31;
  const int half = lane >> 5;
  const float* __restrict__ emb = em + (size_t)b * NT * EST;

  // Etf[l][k] = exp(trans[k][l]); k in [8h,8h+8) and [16+8h,16+8h+8)
  float Et0[8], Et1[8];
#pragma unroll
  for (int j = 0; j < 8; ++j) {
    int k0 = 8 * half + j;
    int k1 = 16 + 8 * half + j;
    Et0[j] = (l < NL) ? __expf(trans[k0 * NL + l]) : 0.f;
    Et1[j] = (l < NL && k1 < NL) ? __expf(trans[k1 * NL + l]) : 0.f;
  }

  // acc = identity in C-layout (fallback if every step masked)
  f32x16 acc;
#pragma unroll
  for (int r = 0; r < 16; ++r) {
    int row = (r & 3) + 8 * (r >> 2) + 4 * half;
    acc[r] = (row == l && l < NL) ? 1.f : 0.f;
  }

  // initial B frags = identity, built through cvt_pk so packing convention
  // matches the steady-state path.
  union Frag { int i[4]; bf16x8 v; };
  Frag B0, B1;
#pragma unroll
  for (int m = 0; m < 4; ++m) {
    int ka = 8 * half + 2 * m, kb = ka + 1;
    B0.i[m] = cvt_pk_bf16((ka == l && l < NL) ? 1.f : 0.f,
                          (kb == l && l < NL) ? 1.f : 0.f);
    int kc = 16 + 8 * half + 2 * m, kd = kc + 1;
    B1.i[m] = cvt_pk_bf16((kc == l && l < NL) ? 1.f : 0.f,
                          (kd == l && l < NL) ? 1.f : 0.f);
  }

  const int ts = 1 + s * SEGLEN;
  const int te = (ts + SEGLEN < NT) ? ts + SEGLEN : NT;
  const int c2 = (l < NL) ? l : NL;  // lanes l>=25 fetch the mask slot

  float c = 0.f, sc = 1.f, ei_ln2 = 0.f;

  float p0 = emb[ts * EST + c2];
  int i1 = ts + 1 < te ? ts + 1 : te - 1;
  int i2 = ts + 2 < te ? ts + 2 : te - 1;
  int i3 = ts + 3 < te ? ts + 3 : te - 1;
  float p1 = emb[i1 * EST + c2];
  float p2 = emb[i2 * EST + c2];
  float p3 = emb[i3 * EST + c2];

  for (int t = ts; t < te; ++t) {
    float emv = p0; p0 = p1; p1 = p2; p2 = p3;
    int tp = t + 4 < te ? t + 4 : te - 1;
    p3 = emb[tp * EST + c2];

    float mv = readlane_f(emv, 25);  // maskf[t]
    if (mv > 0.f) {
      float g = __expf(emv) * sc;  // pending rescale folded into A row scale
      c += ei_ln2;
      sc = 1.f; ei_ln2 = 0.f;

      Frag A0, A1;
#pragma unroll
      for (int m = 0; m < 4; ++m) {
        A0.i[m] = cvt_pk_bf16(Et0[2 * m] * g, Et0[2 * m + 1] * g);
        A1.i[m] = cvt_pk_bf16(Et1[2 * m] * g, Et1[2 * m + 1] * g);
      }
      f32x16 z;
#pragma unroll
      for (int r = 0; r < 16; ++r) z[r] = 0.f;
      z = __builtin_amdgcn_mfma_f32_32x32x16_bf16(A0.v, B0.v, z, 0, 0, 0);
      acc = __builtin_amdgcn_mfma_f32_32x32x16_bf16(A1.v, B1.v, z, 0, 0, 0);

      if ((t & 7) == 7) {  // resample rescale every 8 steps (delayed apply)
        float a0s = readlane_f(acc[0], 0);
        int eb = (__float_as_int(a0s) >> 23) & 255;
        int ei = (eb == 0) ? 0 : eb - 127;
        sc = __int_as_float((127 - ei) << 23);
        ei_ln2 = (float)ei * 0.6931471805599453f;
      }

      // acc (f32 C-layout) -> next-step B frags (bf16)
      int u0 = cvt_pk_bf16(acc[0], acc[1]);
      int u1 = cvt_pk_bf16(acc[2], acc[3]);
      int w0 = cvt_pk_bf16(acc[4], acc[5]);
      int w1 = cvt_pk_bf16(acc[6], acc[7]);
      asm volatile("v_permlane32_swap_b32 %0, %1" : "+v"(u0), "+v"(w0));
      asm volatile("v_permlane32_swap_b32 %0, %1" : "+v"(u1), "+v"(w1));
      B0.i[0] = u0; B0.i[1] = u1; B0.i[2] = w0; B0.i[3] = w1;
      int v0 = cvt_pk_bf16(acc[8], acc[9]);
      int v1 = cvt_pk_bf16(acc[10], acc[11]);
      int x0 = cvt_pk_bf16(acc[12], acc[13]);
      int x1 = cvt_pk_bf16(acc[14], acc[15]);
      asm volatile("v_permlane32_swap_b32 %0, %1" : "+v"(v0), "+v"(x0));
      asm volatile("v_permlane32_swap_b32 %0, %1" : "+v"(v1), "+v"(x1));
      B1.i[0] = v0; B1.i[1] = v1; B1.i[2] = x0; B1.i[3] = x1;
    }
  }

  float* dst = Dg + (size_t)(b * SEGS + s) * 32 * 32;
#pragma unroll
  for (int r = 0; r < 16; ++r) {
    int row = (r & 3) + 8 * (r >> 2) + 4 * half;
    dst[row * 32 + l] = acc[r];
  }
  if (lane == 0) Dc[b * SEGS + s] = c;
}

// Kernel 2b: merge. One wave per chain: numerator + alpha0 x (32 segment mats).
__global__ __launch_bounds__(64) void crf_merge_kernel(
    const float* __restrict__ em, const int* __restrict__ labels,
    const int* __restrict__ mask, const float* __restrict__ trans,
    const float* __restrict__ start_t, const float* __restrict__ end_t,
    const float* __restrict__ Dg, const float* __restrict__ Dc,
    float* __restrict__ out) {
  const int b = blockIdx.x;
  const int lane = threadIdx.x;
  const float* __restrict__ emb = em + (size_t)b * NT * EST;
  const int* __restrict__ lb = labels + b * NT;
  const int* __restrict__ mk = mask + b * NT;

  // ---- numerator ----
  float np = 0.f;
  int ms = 0;
#pragma unroll
  for (int i = 0; i < 8; ++i) {
    int t = lane + i * 64;
    int tag = lb[t];
    int m = mk[t];
    float emt = emb[t * EST + tag];
    ms += m;
    if (t == 0) {
      np += start_t[tag] + emt;
    } else {
      int tagp = lb[t - 1];
      np += (trans[tagp * NL + tag] + emt) * (float)m;
    }
  }
#pragma unroll
  for (int off = 32; off > 0; off >>= 1) {
    np += __shfl_down(np, off, 64);
    ms += __shfl_down(ms, off, 64);
  }
  float num = 0.f;
  if (lane == 0) num = np + end_t[lb[ms - 1]];

  // ---- alpha through SEGS composed segment matrices ----
  const int l = lane & 31;
  float a = (lane < NL) ? __expf(start_t[lane] + emb[lane]) : 0.f;
  float c = 0.f;
  for (int s = 0; s < SEGS; ++s) {
    const float* Drow = Dg + ((size_t)(b * SEGS + s) * 32 + l) * 32;
    float a0 = 0.f, a1 = 0.f, a2 = 0.f, a3 = 0.f;
#pragma unroll
    for (int i = 0; i < NL; i += 4) {
      a0 = fmaf(Drow[i], readlane_f(a, i), a0);
      if (i + 1 < NL) a1 = fmaf(Drow[i + 1], readlane_f(a, i + 1), a1);
      if (i + 2 < NL) a2 = fmaf(Drow[i + 2], readlane_f(a, i + 2), a2);
      if (i + 3 < NL) a3 = fmaf(Drow[i + 3], readlane_f(a, i + 3), a3);
    }
    float an = (a0 + a1) + (a2 + a3);
    c += Dc[b * SEGS + s];
    float s0 = readlane_f(an, 0);
    int eb = (__float_as_int(s0) >> 23) & 255;
    int ei = (eb == 0) ? 0 : eb - 127;
    a = an * __int_as_float((127 - ei) << 23);
    c += (float)ei * 0.6931471805599453f;
  }

  float v = (lane < NL) ? a * __expf(end_t[lane]) : 0.f;
#pragma unroll
  for (int off = 32; off > 0; off >>= 1) v += __shfl_down(v, off, 64);
  if (lane == 0) {
    float denom = c + __logf(v);
    atomicAdd(out, (denom - num) * (1.0f / (float)NB));
  }
}

// Fallback serial CRF (proven exact) — used only if ws_size is too small.
__global__ __launch_bounds__(64) void crf_kernel(
    const float* __restrict__ em, const int* __restrict__ labels,
    const int* __restrict__ mask, const float* __restrict__ trans,
    const float* __restrict__ start_t, const float* __restrict__ end_t,
    float* __restrict__ out) {
  const int b = blockIdx.x;
  const int lane = threadIdx.x;
  const int l = lane < NL ? lane : NL - 1;
  const float* __restrict__ emb = em + (size_t)b * NT * EST;
  const int* __restrict__ lb = labels + b * NT;
  const int* __restrict__ mk = mask + b * NT;

  float np = 0.f;
  int ms = 0;
#pragma unroll
  for (int i = 0; i < 8; ++i) {
    int t = lane + i * 64;
    int tag = lb[t];
    int m = mk[t];
    float emt = emb[t * EST + tag];
    ms += m;
    if (t == 0) np += start_t[tag] + emt;
    else {
      int tagp = lb[t - 1];
      np += (trans[tagp * NL + tag] + emt) * (float)m;
    }
  }
#pragma unroll
  for (int off = 32; off > 0; off >>= 1) {
    np += __shfl_down(np, off, 64);
    ms += __shfl_down(ms, off, 64);
  }
  float num = 0.f;
  if (lane == 0) num = np + end_t[lb[ms - 1]];

  float Ecol[NL];
#pragma unroll
  for (int k = 0; k < NL; ++k) Ecol[k] = __expf(trans[k * NL + l]);

  float A = __expf(start_t[l] + emb[l]);
  float c = 0.f, sc = 1.f, ei_ln2 = 0.f;
  const int j = lane < NL ? lane : NL;

  float p1 = emb[1 * EST + j];
  float p2 = emb[2 * EST + j];
  float p3 = emb[3 * EST + j];
  float p4 = emb[4 * EST + j];

  for (int t = 1; t < NT; ++t) {
    float emv = p1;
    p1 = p2; p2 = p3; p3 = p4;
    int tp = t + 4; tp = tp < NT ? tp : NT - 1;
    p4 = emb[tp * EST + j];
    float e_em = __expf(emv);
    float Pv0 = 0.f, Pv1 = 0.f, Pv2 = 0.f, Pv3 = 0.f;
#pragma unroll
    for (int k = 0; k < NL; k += 4) {
      Pv0 = fmaf(readlane_f(A, k), Ecol[k], Pv0);
      if (k + 1 < NL) Pv1 = fmaf(readlane_f(A, k + 1), Ecol[k + 1], Pv1);
      if (k + 2 < NL) Pv2 = fmaf(readlane_f(A, k + 2), Ecol[k + 2], Pv2);
      if (k + 3 < NL) Pv3 = fmaf(readlane_f(A, k + 3), Ecol[k + 3], Pv3);
    }
    float g = ((Pv0 + Pv1) + (Pv2 + Pv3)) * e_em;
    float mfv = readlane_f(emv, 25);
    float An = (mfv > 0.f) ? g : A;
    A = An * sc;
    c += ei_ln2;
    float a0 = readlane_f(A, 0);
    int eb = (__float_as_int(a0) >> 23) & 255;
    int ei = (eb == 0) ? 0 : (eb - 127);
    sc = __int_as_float((127 - ei) << 23);
    ei_ln2 = (float)ei * 0.6931471805599453f;
  }

  float v = (lane < NL) ? A * __expf(end_t[l]) : 0.f;
#pragma unroll
  for (int off = 32; off > 0; off >>= 1) v += __shfl_down(v, off, 64);
  if (lane == 0) {
    float denom = c + __logf(v);
    atomicAdd(out, (denom - num) * (1.0f / (float)NB));
  }
}

extern "C" void kernel_launch(void* const* d_in, const int* in_sizes, int n_in,
                              void* d_out, int out_size, void* d_ws, size_t ws_size,
                              hipStream_t stream) {
  const float* X       = (const float*)d_in[0];
  const int*   mask    = (const int*)d_in[1];
  const int*   labels  = (const int*)d_in[2];
  const float* W       = (const float*)d_in[3];
  const float* bias    = (const float*)d_in[4];
  const float* trans   = (const float*)d_in[5];
  const float* start_t = (const float*)d_in[6];
  const float* end_t   = (const float*)d_in[7];
  float* out = (float*)d_out;

  float* em = (float*)d_ws;                                     // 3.67 MB
  float* Dg = (float*)((char*)d_ws + (4u << 20));               // 8.00 MB
  float* Dc = (float*)((char*)d_ws + (4u << 20) + (8u << 20));  // 8 KB

  hipMemsetAsync(out, 0, sizeof(float), stream);
  emis_mfma_kernel<<<512, 256, 0, stream>>>(X, mask, W, bias, em);
  if (ws_size >= (13u << 20)) {
    crf_seg_kernel<<<NB * SEGS, 64, 0, stream>>>(em, trans, Dg, Dc);
    crf_merge_kernel<<<NB, 64, 0, stream>>>(em, labels, mask, trans, start_t,
                                            end_t, Dg, Dc, out);
  } else {
    crf_kernel<<<NB, 64, 0, stream>>>(em, labels, mask, trans, start_t, end_t, out);
  }
}

// Round 6
// 198.228 us; speedup vs baseline: 1.6355x; 1.0022x over previous
//
#include <hip/hip_runtime.h>
#include <hip/hip_bf16.h>

#define NB 64
#define NT 512
#define NH 768
#define NL 25
#define EST 28  // emission row stride in floats (16B aligned); slot 25 = maskf
#define SEGS 32
#define SEGLEN 16

typedef __attribute__((ext_vector_type(8))) short bf16x8;
typedef __attribute__((ext_vector_type(4))) float f32x4;
typedef __attribute__((ext_vector_type(16))) float f32x16;

union Frag { int i[4]; bf16x8 v; };

__device__ __forceinline__ float readlane_f(float v, int k) {
  return __int_as_float(__builtin_amdgcn_readlane(__float_as_int(v), k));
}

__device__ __forceinline__ short f2bf(float x) {  // fp32 -> bf16 bits, RNE
  uint32_t u = __float_as_uint(x);
  uint32_t r = (u + 0x7fffu + ((u >> 16) & 1u)) >> 16;
  return (short)r;
}

__device__ __forceinline__ int cvt_pk_bf16(float lo, float hi) {
  int r;
  asm("v_cvt_pk_bf16_f32 %0, %1, %2" : "=v"(r) : "v"(lo), "v"(hi));
  return r;
}

// Kernel 0: pack W into MFMA B-fragments once. 3072 frags = [2][24][64] bf16x8.
// Frag (nt,ks,lane): col=(lane&15)+nt*16, k=ks*32+(lane>>4)*8+j, j=0..7.
__global__ __launch_bounds__(256) void pack_w_kernel(
    const float* __restrict__ W, bf16x8* __restrict__ Wp) {
  int idx = blockIdx.x * 256 + threadIdx.x;  // [0, 3072)
  int nt = idx / (24 * 64);
  int rem = idx - nt * (24 * 64);
  int ks = rem >> 6;
  int sl = rem & 63;
  int col = (sl & 15) + nt * 16;
  int kb = ks * 32 + (sl >> 4) * 8;
  Frag f;
#pragma unroll
  for (int m = 0; m < 4; ++m) {
    float lo = (col < NL) ? W[(kb + 2 * m) * NL + col] : 0.f;
    float hi = (col < NL) ? W[(kb + 2 * m + 1) * NL + col] : 0.f;
    f.i[m] = cvt_pk_bf16(lo, hi);
  }
  Wp[idx] = f.v;
}

// Kernel 1 (MFMA, no LDS): em[row][l] = X[row,:].W[:,l] + b[l]; em[25]=maskf.
// 2048 blocks x 1 wave, 16 rows per wave. B-frags streamed from prepacked Wp
// (L2-resident 48 KB, lane-contiguous dwordx4). A-frags: X fp32 -> bf16 via
// v_cvt_pk_bf16_f32 (RNE). C/D: col=lane&15, row=(lane>>4)*4+reg (m89).
__global__ __launch_bounds__(64) void emis_nolds_kernel(
    const float* __restrict__ X, const int* __restrict__ mask,
    const bf16x8* __restrict__ Wp, const float* __restrict__ bias,
    float* __restrict__ em) {
  const int lane = threadIdx.x;
  const int rowTile = blockIdx.x * 16;
  const int row = rowTile + (lane & 15);
  const int koff = (lane >> 4) * 8;
  const float4* __restrict__ xr = (const float4*)(X + (size_t)row * NH + koff);
  const bf16x8* __restrict__ w0 = Wp + lane;            // [0][ks][lane]
  const bf16x8* __restrict__ w1 = Wp + 24 * 64 + lane;  // [1][ks][lane]

  f32x4 acc0 = {0.f, 0.f, 0.f, 0.f};
  f32x4 acc1 = {0.f, 0.f, 0.f, 0.f};
#pragma unroll 4
  for (int ks = 0; ks < 24; ++ks) {
    float4 xa = xr[ks * 8];
    float4 xb = xr[ks * 8 + 1];
    bf16x8 b0 = w0[ks * 64];
    bf16x8 b1 = w1[ks * 64];
    Frag a;
    a.i[0] = cvt_pk_bf16(xa.x, xa.y);
    a.i[1] = cvt_pk_bf16(xa.z, xa.w);
    a.i[2] = cvt_pk_bf16(xb.x, xb.y);
    a.i[3] = cvt_pk_bf16(xb.z, xb.w);
    acc0 = __builtin_amdgcn_mfma_f32_16x16x32_bf16(a.v, b0, acc0, 0, 0, 0);
    acc1 = __builtin_amdgcn_mfma_f32_16x16x32_bf16(a.v, b1, acc1, 0, 0, 0);
  }

  const int cg = lane & 15;
  const int rbase = rowTile + (lane >> 4) * 4;
  float b0v = bias[cg];
  float b1v = (cg < 9) ? bias[16 + cg] : 0.f;
#pragma unroll
  for (int r = 0; r < 4; ++r) {
    int ro = rbase + r;
    float* er = em + (size_t)ro * EST;
    er[cg] = acc0[r] + b0v;
    if (cg < 9)       er[16 + cg] = acc1[r] + b1v;
    else if (cg == 9) er[25] = (float)mask[ro];
  }
}

// Fallback emis (LDS staging) — only used if ws lacks room for Wp.
__global__ __launch_bounds__(256) void emis_mfma_kernel(
    const float* __restrict__ X, const int* __restrict__ mask,
    const float* __restrict__ W, const float* __restrict__ bias,
    float* __restrict__ em) {
  __shared__ bf16x8 Bf[2][24][64];  // 48 KB
  const int tid = threadIdx.x;

#pragma unroll
  for (int it = 0; it < 12; ++it) {
    int idx = tid + it * 256;
    int nt = idx / (24 * 64);
    int rem = idx - nt * (24 * 64);
    int ks = rem >> 6;
    int sl = rem & 63;
    int col = (sl & 15) + nt * 16;
    int kb = ks * 32 + (sl >> 4) * 8;
    bf16x8 f;
#pragma unroll
    for (int j = 0; j < 8; ++j) {
      float v = (col < NL) ? W[(kb + j) * NL + col] : 0.f;
      f[j] = f2bf(v);
    }
    Bf[nt][ks][sl] = f;
  }
  __syncthreads();

  const int wave = tid >> 6;
  const int lane = tid & 63;
  const int rowTile = blockIdx.x * 64 + wave * 16;
  const int row = rowTile + (lane & 15);
  const int koff = (lane >> 4) * 8;
  const float4* __restrict__ xr = (const float4*)(X + (size_t)row * NH + koff);

  f32x4 acc0 = {0.f, 0.f, 0.f, 0.f};
  f32x4 acc1 = {0.f, 0.f, 0.f, 0.f};
#pragma unroll 4
  for (int ks = 0; ks < 24; ++ks) {
    float4 xa = xr[ks * 8];
    float4 xb = xr[ks * 8 + 1];
    bf16x8 a;
    a[0] = f2bf(xa.x); a[1] = f2bf(xa.y); a[2] = f2bf(xa.z); a[3] = f2bf(xa.w);
    a[4] = f2bf(xb.x); a[5] = f2bf(xb.y); a[6] = f2bf(xb.z); a[7] = f2bf(xb.w);
    bf16x8 b0 = Bf[0][ks][lane];
    bf16x8 b1 = Bf[1][ks][lane];
    acc0 = __builtin_amdgcn_mfma_f32_16x16x32_bf16(a, b0, acc0, 0, 0, 0);
    acc1 = __builtin_amdgcn_mfma_f32_16x16x32_bf16(a, b1, acc1, 0, 0, 0);
  }

  const int cg = lane & 15;
  const int rbase = rowTile + (lane >> 4) * 4;
  float b0v = bias[cg];
  float b1v = (cg < 9) ? bias[16 + cg] : 0.f;
#pragma unroll
  for (int r = 0; r < 4; ++r) {
    int ro = rbase + r;
    float* er = em + (size_t)ro * EST;
    er[cg] = acc0[r] + b0v;
    if (cg < 9)       er[16 + cg] = acc1[r] + b1v;
    else if (cg == 9) er[25] = (float)mask[ro];
  }
}

// Kernel 2a: segment composition. Block = (chain b, segment s), 1 wave.
// D (32x32, rows=dest label l, cols=source label i) evolves as D <- E_t^T x D
// in scaled-exp domain via 2x mfma_f32_32x32x16_bf16 (K split 0..15 / 16..31).
__global__ __launch_bounds__(64) void crf_seg_kernel(
    const float* __restrict__ em, const float* __restrict__ trans,
    float* __restrict__ Dg, float* __restrict__ Dc) {
  const int b = blockIdx.x / SEGS;
  const int s = blockIdx.x % SEGS;
  const int lane = threadIdx.x;
  const int l = lane & 31;
  const int half = lane >> 5;
  const float* __restrict__ emb = em + (size_t)b * NT * EST;

  // Etf[l][k] = exp(trans[k][l]); k in [8h,8h+8) and [16+8h,16+8h+8)
  float Et0[8], Et1[8];
#pragma unroll
  for (int j = 0; j < 8; ++j) {
    int k0 = 8 * half + j;
    int k1 = 16 + 8 * half + j;
    Et0[j] = (l < NL) ? __expf(trans[k0 * NL + l]) : 0.f;
    Et1[j] = (l < NL && k1 < NL) ? __expf(trans[k1 * NL + l]) : 0.f;
  }

  // acc = identity in C-layout (fallback if every step masked)
  f32x16 acc;
#pragma unroll
  for (int r = 0; r < 16; ++r) {
    int row = (r & 3) + 8 * (r >> 2) + 4 * half;
    acc[r] = (row == l && l < NL) ? 1.f : 0.f;
  }

  // initial B frags = identity, built through cvt_pk so packing convention
  // matches the steady-state path.
  Frag B0, B1;
#pragma unroll
  for (int m = 0; m < 4; ++m) {
    int ka = 8 * half + 2 * m, kb = ka + 1;
    B0.i[m] = cvt_pk_bf16((ka == l && l < NL) ? 1.f : 0.f,
                          (kb == l && l < NL) ? 1.f : 0.f);
    int kc = 16 + 8 * half + 2 * m, kd = kc + 1;
    B1.i[m] = cvt_pk_bf16((kc == l && l < NL) ? 1.f : 0.f,
                          (kd == l && l < NL) ? 1.f : 0.f);
  }

  const int ts = 1 + s * SEGLEN;
  const int te = (ts + SEGLEN < NT) ? ts + SEGLEN : NT;
  const int c2 = (l < NL) ? l : NL;  // lanes l>=25 fetch the mask slot

  float c = 0.f, sc = 1.f, ei_ln2 = 0.f;

  float p0 = emb[ts * EST + c2];
  int i1 = ts + 1 < te ? ts + 1 : te - 1;
  int i2 = ts + 2 < te ? ts + 2 : te - 1;
  int i3 = ts + 3 < te ? ts + 3 : te - 1;
  float p1 = emb[i1 * EST + c2];
  float p2 = emb[i2 * EST + c2];
  float p3 = emb[i3 * EST + c2];

  for (int t = ts; t < te; ++t) {
    float emv = p0; p0 = p1; p1 = p2; p2 = p3;
    int tp = t + 4 < te ? t + 4 : te - 1;
    p3 = emb[tp * EST + c2];

    float mv = readlane_f(emv, 25);  // maskf[t]
    if (mv > 0.f) {
      float g = __expf(emv) * sc;  // pending rescale folded into A row scale
      c += ei_ln2;
      sc = 1.f; ei_ln2 = 0.f;

      Frag A0, A1;
#pragma unroll
      for (int m = 0; m < 4; ++m) {
        A0.i[m] = cvt_pk_bf16(Et0[2 * m] * g, Et0[2 * m + 1] * g);
        A1.i[m] = cvt_pk_bf16(Et1[2 * m] * g, Et1[2 * m + 1] * g);
      }
      f32x16 z;
#pragma unroll
      for (int r = 0; r < 16; ++r) z[r] = 0.f;
      z = __builtin_amdgcn_mfma_f32_32x32x16_bf16(A0.v, B0.v, z, 0, 0, 0);
      acc = __builtin_amdgcn_mfma_f32_32x32x16_bf16(A1.v, B1.v, z, 0, 0, 0);

      if ((t & 7) == 7) {  // resample rescale every 8 steps (delayed apply)
        float a0s = readlane_f(acc[0], 0);
        int eb = (__float_as_int(a0s) >> 23) & 255;
        int ei = (eb == 0) ? 0 : eb - 127;
        sc = __int_as_float((127 - ei) << 23);
        ei_ln2 = (float)ei * 0.6931471805599453f;
      }

      // acc (f32 C-layout) -> next-step B frags (bf16)
      int u0 = cvt_pk_bf16(acc[0], acc[1]);
      int u1 = cvt_pk_bf16(acc[2], acc[3]);
      int w0 = cvt_pk_bf16(acc[4], acc[5]);
      int w1 = cvt_pk_bf16(acc[6], acc[7]);
      asm volatile("v_permlane32_swap_b32 %0, %1" : "+v"(u0), "+v"(w0));
      asm volatile("v_permlane32_swap_b32 %0, %1" : "+v"(u1), "+v"(w1));
      B0.i[0] = u0; B0.i[1] = u1; B0.i[2] = w0; B0.i[3] = w1;
      int v0 = cvt_pk_bf16(acc[8], acc[9]);
      int v1 = cvt_pk_bf16(acc[10], acc[11]);
      int x0 = cvt_pk_bf16(acc[12], acc[13]);
      int x1 = cvt_pk_bf16(acc[14], acc[15]);
      asm volatile("v_permlane32_swap_b32 %0, %1" : "+v"(v0), "+v"(x0));
      asm volatile("v_permlane32_swap_b32 %0, %1" : "+v"(v1), "+v"(x1));
      B1.i[0] = v0; B1.i[1] = v1; B1.i[2] = x0; B1.i[3] = x1;
    }
  }

  float* dst = Dg + (size_t)(b * SEGS + s) * 32 * 32;
#pragma unroll
  for (int r = 0; r < 16; ++r) {
    int row = (r & 3) + 8 * (r >> 2) + 4 * half;
    dst[row * 32 + l] = acc[r];
  }
  if (lane == 0) Dc[b * SEGS + s] = c;
}

// Kernel 2b: merge. One wave per chain: numerator + alpha0 x (32 segment mats).
__global__ __launch_bounds__(64) void crf_merge_kernel(
    const float* __restrict__ em, const int* __restrict__ labels,
    const int* __restrict__ mask, const float* __restrict__ trans,
    const float* __restrict__ start_t, const float* __restrict__ end_t,
    const float* __restrict__ Dg, const float* __restrict__ Dc,
    float* __restrict__ out) {
  const int b = blockIdx.x;
  const int lane = threadIdx.x;
  const float* __restrict__ emb = em + (size_t)b * NT * EST;
  const int* __restrict__ lb = labels + b * NT;
  const int* __restrict__ mk = mask + b * NT;

  // ---- numerator ----
  float np = 0.f;
  int ms = 0;
#pragma unroll
  for (int i = 0; i < 8; ++i) {
    int t = lane + i * 64;
    int tag = lb[t];
    int m = mk[t];
    float emt = emb[t * EST + tag];
    ms += m;
    if (t == 0) {
      np += start_t[tag] + emt;
    } else {
      int tagp = lb[t - 1];
      np += (trans[tagp * NL + tag] + emt) * (float)m;
    }
  }
#pragma unroll
  for (int off = 32; off > 0; off >>= 1) {
    np += __shfl_down(np, off, 64);
    ms += __shfl_down(ms, off, 64);
  }
  float num = 0.f;
  if (lane == 0) num = np + end_t[lb[ms - 1]];

  // ---- alpha through SEGS composed segment matrices ----
  const int l = lane & 31;
  float a = (lane < NL) ? __expf(start_t[lane] + emb[lane]) : 0.f;
  float c = 0.f;
  for (int s = 0; s < SEGS; ++s) {
    const float* Drow = Dg + ((size_t)(b * SEGS + s) * 32 + l) * 32;
    float a0 = 0.f, a1 = 0.f, a2 = 0.f, a3 = 0.f;
#pragma unroll
    for (int i = 0; i < NL; i += 4) {
      a0 = fmaf(Drow[i], readlane_f(a, i), a0);
      if (i + 1 < NL) a1 = fmaf(Drow[i + 1], readlane_f(a, i + 1), a1);
      if (i + 2 < NL) a2 = fmaf(Drow[i + 2], readlane_f(a, i + 2), a2);
      if (i + 3 < NL) a3 = fmaf(Drow[i + 3], readlane_f(a, i + 3), a3);
    }
    float an = (a0 + a1) + (a2 + a3);
    c += Dc[b * SEGS + s];
    float s0 = readlane_f(an, 0);
    int eb = (__float_as_int(s0) >> 23) & 255;
    int ei = (eb == 0) ? 0 : eb - 127;
    a = an * __int_as_float((127 - ei) << 23);
    c += (float)ei * 0.6931471805599453f;
  }

  float v = (lane < NL) ? a * __expf(end_t[lane]) : 0.f;
#pragma unroll
  for (int off = 32; off > 0; off >>= 1) v += __shfl_down(v, off, 64);
  if (lane == 0) {
    float denom = c + __logf(v);
    atomicAdd(out, (denom - num) * (1.0f / (float)NB));
  }
}

// Fallback serial CRF (proven exact) — used only if ws_size is too small.
__global__ __launch_bounds__(64) void crf_kernel(
    const float* __restrict__ em, const int* __restrict__ labels,
    const int* __restrict__ mask, const float* __restrict__ trans,
    const float* __restrict__ start_t, const float* __restrict__ end_t,
    float* __restrict__ out) {
  const int b = blockIdx.x;
  const int lane = threadIdx.x;
  const int l = lane < NL ? lane : NL - 1;
  const float* __restrict__ emb = em + (size_t)b * NT * EST;
  const int* __restrict__ lb = labels + b * NT;
  const int* __restrict__ mk = mask + b * NT;

  float np = 0.f;
  int ms = 0;
#pragma unroll
  for (int i = 0; i < 8; ++i) {
    int t = lane + i * 64;
    int tag = lb[t];
    int m = mk[t];
    float emt = emb[t * EST + tag];
    ms += m;
    if (t == 0) np += start_t[tag] + emt;
    else {
      int tagp = lb[t - 1];
      np += (trans[tagp * NL + tag] + emt) * (float)m;
    }
  }
#pragma unroll
  for (int off = 32; off > 0; off >>= 1) {
    np += __shfl_down(np, off, 64);
    ms += __shfl_down(ms, off, 64);
  }
  float num = 0.f;
  if (lane == 0) num = np + end_t[lb[ms - 1]];

  float Ecol[NL];
#pragma unroll
  for (int k = 0; k < NL; ++k) Ecol[k] = __expf(trans[k * NL + l]);

  float A = __expf(start_t[l] + emb[l]);
  float c = 0.f, sc = 1.f, ei_ln2 = 0.f;
  const int j = lane < NL ? lane : NL;

  float p1 = emb[1 * EST + j];
  float p2 = emb[2 * EST + j];
  float p3 = emb[3 * EST + j];
  float p4 = emb[4 * EST + j];

  for (int t = 1; t < NT; ++t) {
    float emv = p1;
    p1 = p2; p2 = p3; p3 = p4;
    int tp = t + 4; tp = tp < NT ? tp : NT - 1;
    p4 = emb[tp * EST + j];
    float e_em = __expf(emv);
    float Pv0 = 0.f, Pv1 = 0.f, Pv2 = 0.f, Pv3 = 0.f;
#pragma unroll
    for (int k = 0; k < NL; k += 4) {
      Pv0 = fmaf(readlane_f(A, k), Ecol[k], Pv0);
      if (k + 1 < NL) Pv1 = fmaf(readlane_f(A, k + 1), Ecol[k + 1], Pv1);
      if (k + 2 < NL) Pv2 = fmaf(readlane_f(A, k + 2), Ecol[k + 2], Pv2);
      if (k + 3 < NL) Pv3 = fmaf(readlane_f(A, k + 3), Ecol[k + 3], Pv3);
    }
    float g = ((Pv0 + Pv1) + (Pv2 + Pv3)) * e_em;
    float mfv = readlane_f(emv, 25);
    float An = (mfv > 0.f) ? g : A;
    A = An * sc;
    c += ei_ln2;
    float a0 = readlane_f(A, 0);
    int eb = (__float_as_int(a0) >> 23) & 255;
    int ei = (eb == 0) ? 0 : (eb - 127);
    sc = __int_as_float((127 - ei) << 23);
    ei_ln2 = (float)ei * 0.6931471805599453f;
  }

  float v = (lane < NL) ? A * __expf(end_t[l]) : 0.f;
#pragma unroll
  for (int off = 32; off > 0; off >>= 1) v += __shfl_down(v, off, 64);
  if (lane == 0) {
    float denom = c + __logf(v);
    atomicAdd(out, (denom - num) * (1.0f / (float)NB));
  }
}

extern "C" void kernel_launch(void* const* d_in, const int* in_sizes, int n_in,
                              void* d_out, int out_size, void* d_ws, size_t ws_size,
                              hipStream_t stream) {
  const float* X       = (const float*)d_in[0];
  const int*   mask    = (const int*)d_in[1];
  const int*   labels  = (const int*)d_in[2];
  const float* W       = (const float*)d_in[3];
  const float* bias    = (const float*)d_in[4];
  const float* trans   = (const float*)d_in[5];
  const float* start_t = (const float*)d_in[6];
  const float* end_t   = (const float*)d_in[7];
  float* out = (float*)d_out;

  char* ws = (char*)d_ws;
  float*  em = (float*)ws;                          // 3.67 MB @ 0
  float*  Dg = (float*)(ws + (4u << 20));           // 8.00 MB @ 4M
  float*  Dc = (float*)(ws + (12u << 20));          // 8 KB   @ 12M
  bf16x8* Wp = (bf16x8*)(ws + (12u << 20) + 65536); // 48 KB  @ 12M+64K

  hipMemsetAsync(out, 0, sizeof(float), stream);
  if (ws_size >= (14u << 20)) {
    pack_w_kernel<<<12, 256, 0, stream>>>(W, Wp);
    emis_nolds_kernel<<<2048, 64, 0, stream>>>(X, mask, Wp, bias, em);
    crf_seg_kernel<<<NB * SEGS, 64, 0, stream>>>(em, trans, Dg, Dc);
    crf_merge_kernel<<<NB, 64, 0, stream>>>(em, labels, mask, trans, start_t,
                                            end_t, Dg, Dc, out);
  } else {
    emis_mfma_kernel<<<512, 256, 0, stream>>>(X, mask, W, bias, em);
    crf_kernel<<<NB, 64, 0, stream>>>(em, labels, mask, trans, start_t, end_t, out);
  }
}